// Round 1
// baseline (382.889 us; speedup 1.0000x reference)
//
#include <hip/hip_runtime.h>
#include <hip/hip_bf16.h>
#include <cstdint>

// ---------------------------------------------------------------------------
// SelfAttention fused block: B=4, S=2048, D=1024, fp32 in/out.
// Strategy: bf16 MFMA GEMMs (m97-structure 128x128 tile, global_load_lds w=16),
// fp32 softmax + fused GLU/LayerNorm epilogues.
// ---------------------------------------------------------------------------

typedef __bf16 bf16x8 __attribute__((ext_vector_type(8)));
typedef float f32x4 __attribute__((ext_vector_type(4)));

__device__ __forceinline__ void gload_lds16(const void* g, void* l) {
    __builtin_amdgcn_global_load_lds(
        (__attribute__((address_space(1))) void*)(uintptr_t)g,
        (__attribute__((address_space(3))) void*)(uintptr_t)l,
        16, 0, 0);
}

__device__ __forceinline__ float to_f32(float x) { return x; }
__device__ __forceinline__ float to_f32(__hip_bfloat16 x) { return __bfloat162float(x); }

// ---------------------------------------------------------------------------
// GEMM: C[m,n] = sum_k A[m,k] * Bt[n,k]   (A row-major [M][K], Bt row-major [N][K])
// EPI 0: bf16 out = acc + bias ; EPI 1: f32 out = acc*scale ; EPI 2: f32 out = acc + bias
// Block 256 thr = 4 waves (2x2), wave tile 64x64 (4x4 frags of 16x16x32 bf16 MFMA).
// ---------------------------------------------------------------------------
template <int EPI>
__global__ __launch_bounds__(256) void gemm_bt(
    const __hip_bfloat16* __restrict__ A, const __hip_bfloat16* __restrict__ Bt,
    void* __restrict__ Cout, const float* __restrict__ bias, float scale,
    int N, int K, long strideA, long strideB, long strideC)
{
    __shared__ __align__(16) __hip_bfloat16 sA[128 * 32];
    __shared__ __align__(16) __hip_bfloat16 sB[128 * 32];

    const int b = blockIdx.z;
    const int tid = threadIdx.x;
    const int lane = tid & 63;
    const int wave = tid >> 6;
    const int wr = wave >> 1, wc = wave & 1;

    const __hip_bfloat16* gA = A + (long)b * strideA + (long)blockIdx.x * 128 * K;
    const __hip_bfloat16* gB = Bt + (long)b * strideB + (long)blockIdx.y * 128 * K;

    f32x4 acc[4][4];
#pragma unroll
    for (int m = 0; m < 4; ++m)
#pragma unroll
        for (int n = 0; n < 4; ++n) acc[m][n] = {0.f, 0.f, 0.f, 0.f};

    for (int k0 = 0; k0 < K; k0 += 32) {
        __syncthreads();  // protect LDS from previous iteration's readers
#pragma unroll
        for (int j = 0; j < 2; ++j) {
            const int c = j * 256 + tid;      // 16B chunk id; LDS dst = wavebase + lane*16 (linear)
            const int r = c >> 2;             // tile row (BK=32 bf16 = 64B = 4 chunks/row)
            const int ks = (c & 3) * 8;       // k element offset
            gload_lds16(gA + (long)r * K + k0 + ks, (char*)sA + c * 16);
            gload_lds16(gB + (long)r * K + k0 + ks, (char*)sB + c * 16);
        }
        __syncthreads();  // compiler drains vmcnt(0) before s_barrier

        const int kg = (lane >> 4) * 8;   // k group of this lane's fragment
        const int fr = lane & 15;         // fragment row/col
        bf16x8 av[4], bv[4];
#pragma unroll
        for (int m = 0; m < 4; ++m)
            av[m] = *(const bf16x8*)(sA + (wr * 64 + m * 16 + fr) * 32 + kg);
#pragma unroll
        for (int n = 0; n < 4; ++n)
            bv[n] = *(const bf16x8*)(sB + (wc * 64 + n * 16 + fr) * 32 + kg);
#pragma unroll
        for (int m = 0; m < 4; ++m)
#pragma unroll
            for (int n = 0; n < 4; ++n)
                acc[m][n] = __builtin_amdgcn_mfma_f32_16x16x32_bf16(av[m], bv[n], acc[m][n], 0, 0, 0);
    }

    // epilogue: C/D layout (m89-verified): col = lane&15, row = (lane>>4)*4 + reg
    const long row0 = (long)blockIdx.x * 128 + wr * 64;
    const long col0 = (long)blockIdx.y * 128 + wc * 64;
    const int cr = (lane >> 4) * 4;
    const int cc = lane & 15;
#pragma unroll
    for (int m = 0; m < 4; ++m) {
#pragma unroll
        for (int n = 0; n < 4; ++n) {
            const long col = col0 + n * 16 + cc;
            const float bval = (EPI != 1 && bias != nullptr) ? bias[col] : 0.f;
#pragma unroll
            for (int i = 0; i < 4; ++i) {
                const long row = row0 + m * 16 + cr + i;
                const float v = acc[m][n][i];
                const long idx = (long)b * strideC + row * (long)N + col;
                if (EPI == 1) {
                    ((float*)Cout)[idx] = v * scale;
                } else if (EPI == 0) {
                    ((__hip_bfloat16*)Cout)[idx] = __float2bfloat16(v + bval);
                } else {
                    ((float*)Cout)[idx] = v + bval;
                }
            }
        }
    }
}

// ---------------------------------------------------------------------------
// out[c][r] = (bf16) in[r][c] ; LDS-tiled 32x32, block (32,8)
// ---------------------------------------------------------------------------
template <typename TIN>
__global__ __launch_bounds__(256) void transpose_to_bf16(
    const TIN* __restrict__ in, __hip_bfloat16* __restrict__ out,
    int R, int C, long sIn, long sOut)
{
    __shared__ float tile[32][33];
    const int b = blockIdx.z;
    const TIN* pin = in + (long)b * sIn;
    __hip_bfloat16* pout = out + (long)b * sOut;
    const int tx = threadIdx.x, ty = threadIdx.y;
    const int c0 = blockIdx.x * 32, r0 = blockIdx.y * 32;
#pragma unroll
    for (int j = 0; j < 4; ++j)
        tile[ty + j * 8][tx] = to_f32(pin[(long)(r0 + ty + j * 8) * C + c0 + tx]);
    __syncthreads();
#pragma unroll
    for (int j = 0; j < 4; ++j)
        pout[(long)(c0 + ty + j * 8) * R + r0 + tx] = __float2bfloat16(tile[tx][ty + j * 8]);
}

// ---------------------------------------------------------------------------
// x (f32) -> bf16, 4 elems/thread
// ---------------------------------------------------------------------------
__global__ __launch_bounds__(256) void f32_to_bf16_vec(
    const float* __restrict__ in, __hip_bfloat16* __restrict__ out, long n4)
{
    const long i = (long)blockIdx.x * 256 + threadIdx.x;
    if (i >= n4) return;
    const float4 v = ((const float4*)in)[i];
    union { __hip_bfloat16 h[4]; ushort4 u; } cv;
    cv.h[0] = __float2bfloat16(v.x);
    cv.h[1] = __float2bfloat16(v.y);
    cv.h[2] = __float2bfloat16(v.z);
    cv.h[3] = __float2bfloat16(v.w);
    ((ushort4*)out)[i] = cv.u;
}

// ---------------------------------------------------------------------------
// row softmax: one block per row of 2048 f32 scores -> bf16 probs
// ---------------------------------------------------------------------------
__global__ __launch_bounds__(256) void softmax_kernel(
    const float* __restrict__ S, __hip_bfloat16* __restrict__ P)
{
    const long row = blockIdx.x;
    const float* s = S + row * 2048;
    __hip_bfloat16* p = P + row * 2048;
    const int t = threadIdx.x;
    float v[8];
    float mx = -1e30f;
#pragma unroll
    for (int j = 0; j < 8; ++j) { v[j] = s[t + j * 256]; mx = fmaxf(mx, v[j]); }
#pragma unroll
    for (int off = 32; off; off >>= 1) mx = fmaxf(mx, __shfl_xor(mx, off));
    __shared__ float wred[4];
    __shared__ float wsum[4];
    const int w = t >> 6;
    if ((t & 63) == 0) wred[w] = mx;
    __syncthreads();
    mx = fmaxf(fmaxf(wred[0], wred[1]), fmaxf(wred[2], wred[3]));
    float sum = 0.f;
#pragma unroll
    for (int j = 0; j < 8; ++j) { v[j] = __expf(v[j] - mx); sum += v[j]; }
#pragma unroll
    for (int off = 32; off; off >>= 1) sum += __shfl_xor(sum, off);
    if ((t & 63) == 0) wsum[w] = sum;
    __syncthreads();
    sum = wsum[0] + wsum[1] + wsum[2] + wsum[3];
    const float inv = 1.0f / sum;
#pragma unroll
    for (int j = 0; j < 8; ++j) p[t + j * 256] = __float2bfloat16(v[j] * inv);
}

// ---------------------------------------------------------------------------
// y = T1 + Gv*sigmoid(Gg); out = LN(y)*gamma + beta.  One block per row (D=1024).
// ---------------------------------------------------------------------------
__global__ __launch_bounds__(256) void glu_ln_kernel(
    const float* __restrict__ T1, const float* __restrict__ Gv, const float* __restrict__ Gg,
    const float* __restrict__ gamma, const float* __restrict__ beta, float* __restrict__ out)
{
    const long base = (long)blockIdx.x * 1024;
    const int t = threadIdx.x;
    float y[4];
    float s = 0.f, ss = 0.f;
#pragma unroll
    for (int j = 0; j < 4; ++j) {
        const int i = t + j * 256;
        const float gg = Gg[base + i];
        const float g = Gv[base + i] * (1.0f / (1.0f + __expf(-gg)));
        const float v = T1[base + i] + g;
        y[j] = v; s += v; ss += v * v;
    }
#pragma unroll
    for (int off = 32; off; off >>= 1) { s += __shfl_xor(s, off); ss += __shfl_xor(ss, off); }
    __shared__ float rs[4], rss[4];
    const int w = t >> 6;
    if ((t & 63) == 0) { rs[w] = s; rss[w] = ss; }
    __syncthreads();
    s = rs[0] + rs[1] + rs[2] + rs[3];
    ss = rss[0] + rss[1] + rss[2] + rss[3];
    const float mu = s * (1.0f / 1024.0f);
    const float var = ss * (1.0f / 1024.0f) - mu * mu;
    const float r = rsqrtf(var + 1e-5f);
#pragma unroll
    for (int j = 0; j < 4; ++j) {
        const int i = t + j * 256;
        out[base + i] = (y[j] - mu) * r * gamma[i] + beta[i];
    }
}

// ---------------------------------------------------------------------------
extern "C" void kernel_launch(void* const* d_in, const int* in_sizes, int n_in,
                              void* d_out, int out_size, void* d_ws, size_t ws_size,
                              hipStream_t stream)
{
    const int B = 4, S = 2048, D = 1024;
    const float* x    = (const float*)d_in[0];
    const float* Wq   = (const float*)d_in[1];
    const float* bq   = (const float*)d_in[2];
    const float* Wk   = (const float*)d_in[3];
    const float* bk   = (const float*)d_in[4];
    const float* Wv   = (const float*)d_in[5];
    const float* bv   = (const float*)d_in[6];
    const float* Wo   = (const float*)d_in[7];
    const float* bo   = (const float*)d_in[8];
    const float* Wgv  = (const float*)d_in[9];
    const float* bgv  = (const float*)d_in[10];
    const float* Wgg  = (const float*)d_in[11];
    const float* bgg  = (const float*)d_in[12];
    const float* gamma = (const float*)d_in[13];
    const float* beta  = (const float*)d_in[14];
    float* out = (float*)d_out;

    char* ws = (char*)d_ws;
    size_t off = 0;
    auto take = [&](size_t bytes) { char* p = ws + off; off += (bytes + 255) & ~(size_t)255; return p; };

    __hip_bfloat16* wt[6];
    for (int i = 0; i < 6; ++i) wt[i] = (__hip_bfloat16*)take((size_t)D * D * 2);  // 12 MiB
    __hip_bfloat16* xb   = (__hip_bfloat16*)take((size_t)B * S * D * 2);           // 16 MiB
    __hip_bfloat16* Qb   = (__hip_bfloat16*)take((size_t)B * S * D * 2);
    __hip_bfloat16* Kb   = (__hip_bfloat16*)take((size_t)B * S * D * 2);
    __hip_bfloat16* Vb   = (__hip_bfloat16*)take((size_t)B * S * D * 2);
    __hip_bfloat16* Vtb  = (__hip_bfloat16*)take((size_t)B * S * D * 2);
    float*          scores = (float*)take((size_t)B * S * S * 4);                  // 64 MiB
    __hip_bfloat16* Pb   = (__hip_bfloat16*)take((size_t)B * S * S * 2);           // 32 MiB
    __hip_bfloat16* Oatt = (__hip_bfloat16*)take((size_t)B * S * D * 2);
    float*          T1   = (float*)take((size_t)B * S * D * 4);                    // 32 MiB
    // scores is dead after softmax -> reuse its 64 MiB for the two GLU GEMM outputs
    float* Gval  = scores;
    float* Ggate = scores + (size_t)B * S * D;

    const long SD = (long)S * D, SS = (long)S * S;
    const float att_scale = 0.03125f;  // 1/sqrt(1024)

    // 1. casts / weight transposes (Wt[e][d] = W[d][e] so every GEMM is bt-format)
    f32_to_bf16_vec<<<dim3((unsigned)((long)B * S * D / 4 / 256)), dim3(256), 0, stream>>>(x, xb, (long)B * S * D / 4);
    const float* Wsrc[6] = {Wq, Wk, Wv, Wo, Wgv, Wgg};
    for (int i = 0; i < 6; ++i)
        transpose_to_bf16<float><<<dim3(D / 32, D / 32, 1), dim3(32, 8), 0, stream>>>(Wsrc[i], wt[i], D, D, 0, 0);

    // 2. Q,K,V projections (bf16 out)
    gemm_bt<0><<<dim3(B * S / 128, D / 128, 1), dim3(256), 0, stream>>>(xb, wt[0], Qb, bq, 1.f, D, D, 0, 0, 0);
    gemm_bt<0><<<dim3(B * S / 128, D / 128, 1), dim3(256), 0, stream>>>(xb, wt[1], Kb, bk, 1.f, D, D, 0, 0, 0);
    gemm_bt<0><<<dim3(B * S / 128, D / 128, 1), dim3(256), 0, stream>>>(xb, wt[2], Vb, bv, 1.f, D, D, 0, 0, 0);

    // 3. scores = scale * Q K^T  (f32), per batch
    gemm_bt<1><<<dim3(S / 128, S / 128, B), dim3(256), 0, stream>>>(Qb, Kb, scores, nullptr, att_scale, S, D, SD, SD, SS);

    // 4. row softmax -> bf16 P
    softmax_kernel<<<dim3(B * S), dim3(256), 0, stream>>>(scores, Pb);

    // 5. V^T per batch, then Oatt = P @ V
    transpose_to_bf16<__hip_bfloat16><<<dim3(D / 32, S / 32, B), dim3(32, 8), 0, stream>>>(Vb, Vtb, S, D, SD, SD);
    gemm_bt<0><<<dim3(S / 128, D / 128, B), dim3(256), 0, stream>>>(Pb, Vtb, Oatt, nullptr, 1.f, D, S, SS, SD, SD);

    // 6. T1 = Oatt @ Wo + bo (f32)
    gemm_bt<2><<<dim3(B * S / 128, D / 128, 1), dim3(256), 0, stream>>>(Oatt, wt[3], T1, bo, 1.f, D, D, 0, 0, 0);

    // 7. GLU branches (f32, into reused scores region)
    gemm_bt<2><<<dim3(B * S / 128, D / 128, 1), dim3(256), 0, stream>>>(Qb, wt[4], Gval, bgv, 1.f, D, D, 0, 0, 0);
    gemm_bt<2><<<dim3(B * S / 128, D / 128, 1), dim3(256), 0, stream>>>(Qb, wt[5], Ggate, bgg, 1.f, D, D, 0, 0, 0);

    // 8. y = T1 + Gval*sigmoid(Ggate); out = LayerNorm(y)*gamma+beta
    glu_ln_kernel<<<dim3(B * S), dim3(256), 0, stream>>>(T1, Gval, Ggate, gamma, beta, out);
}

// Round 3
// 361.983 us; speedup vs baseline: 1.0578x; 1.0578x over previous
//
#include <hip/hip_runtime.h>
#include <hip/hip_bf16.h>
#include <cstdint>

// ---------------------------------------------------------------------------
// SelfAttention fused block: B=4, S=2048, D=1024, fp32 in/out.
// R1 (resubmit after infra failure): fused QKV gemm (N=3072), fused GLU gemm
// (N=2048), LDS XOR-swizzle (pre-swizzled global source + swizzled ds_read;
// LDS linear per rule #21).
// ---------------------------------------------------------------------------

typedef __bf16 bf16x8 __attribute__((ext_vector_type(8)));
typedef float f32x4 __attribute__((ext_vector_type(4)));

__device__ __forceinline__ void gload_lds16(const void* g, void* l) {
    __builtin_amdgcn_global_load_lds(
        (__attribute__((address_space(1))) void*)(uintptr_t)g,
        (__attribute__((address_space(3))) void*)(uintptr_t)l,
        16, 0, 0);
}

__device__ __forceinline__ float to_f32(float x) { return x; }
__device__ __forceinline__ float to_f32(__hip_bfloat16 x) { return __bfloat162float(x); }

// ---------------------------------------------------------------------------
// GEMM: C[m,n] = sum_k A[m,k] * Bt[n,k]
// A row-major [M][lda], Bt row-major [N][ldb], C row stride ldc.
// EPI 0: bf16 out = acc + bias ; EPI 1: f32 out = acc*scale ; EPI 2: f32 out = acc + bias
// Block 256 thr = 4 waves (2x2), wave tile 64x64 (4x4 frags of 16x16x32 bf16 MFMA).
// LDS swizzle: 16B slot within each 64B row XORed with (row>>1)&3 on BOTH the
// global-source side (staging) and the ds_read side; LDS layout stays linear.
// ---------------------------------------------------------------------------
template <int EPI>
__global__ __launch_bounds__(256) void gemm_bt(
    const __hip_bfloat16* __restrict__ A, const __hip_bfloat16* __restrict__ Bt,
    void* __restrict__ Cout, const float* __restrict__ bias, float scale,
    int N, int K, int lda, int ldb, int ldc,
    long strideA, long strideB, long strideC)
{
    __shared__ __align__(16) __hip_bfloat16 sA[128 * 32];
    __shared__ __align__(16) __hip_bfloat16 sB[128 * 32];

    const int b = blockIdx.z;
    const int tid = threadIdx.x;
    const int lane = tid & 63;
    const int wave = tid >> 6;
    const int wr = wave >> 1, wc = wave & 1;

    const __hip_bfloat16* gA = A + (long)b * strideA + (long)blockIdx.x * 128 * lda;
    const __hip_bfloat16* gB = Bt + (long)b * strideB + (long)blockIdx.y * 128 * ldb;

    f32x4 acc[4][4];
#pragma unroll
    for (int m = 0; m < 4; ++m)
#pragma unroll
        for (int n = 0; n < 4; ++n) acc[m][n] = {0.f, 0.f, 0.f, 0.f};

    for (int k0 = 0; k0 < K; k0 += 32) {
        __syncthreads();  // protect LDS from previous iteration's readers
#pragma unroll
        for (int j = 0; j < 2; ++j) {
            const int c = j * 256 + tid;           // 16B chunk id; LDS dst linear
            const int r = c >> 2;                  // tile row (32 bf16 = 64B = 4 chunks)
            const int slot = c & 3;                // 16B slot within row
            const int srcslot = slot ^ ((r >> 1) & 3);  // inverse-swizzled SOURCE
            gload_lds16(gA + (long)r * lda + k0 + srcslot * 8, (char*)sA + c * 16);
            gload_lds16(gB + (long)r * ldb + k0 + srcslot * 8, (char*)sB + c * 16);
        }
        __syncthreads();  // compiler drains vmcnt(0) before s_barrier

        const int sr = lane >> 4;     // 16B slot this lane's fragment wants
        const int fr = lane & 15;     // fragment row/col
        bf16x8 av[4], bv[4];
#pragma unroll
        for (int m = 0; m < 4; ++m) {
            const int row = wr * 64 + m * 16 + fr;
            av[m] = *(const bf16x8*)(sA + row * 32 + (sr ^ ((row >> 1) & 3)) * 8);
        }
#pragma unroll
        for (int n = 0; n < 4; ++n) {
            const int row = wc * 64 + n * 16 + fr;
            bv[n] = *(const bf16x8*)(sB + row * 32 + (sr ^ ((row >> 1) & 3)) * 8);
        }
#pragma unroll
        for (int m = 0; m < 4; ++m)
#pragma unroll
            for (int n = 0; n < 4; ++n)
                acc[m][n] = __builtin_amdgcn_mfma_f32_16x16x32_bf16(av[m], bv[n], acc[m][n], 0, 0, 0);
    }

    // epilogue: C/D layout (m89-verified): col = lane&15, row = (lane>>4)*4 + reg
    const long row0 = (long)blockIdx.x * 128 + wr * 64;
    const long col0 = (long)blockIdx.y * 128 + wc * 64;
    const int cr = (lane >> 4) * 4;
    const int cc = lane & 15;
#pragma unroll
    for (int m = 0; m < 4; ++m) {
#pragma unroll
        for (int n = 0; n < 4; ++n) {
            const long col = col0 + n * 16 + cc;
            const float bval = (EPI != 1 && bias != nullptr) ? bias[col] : 0.f;
#pragma unroll
            for (int i = 0; i < 4; ++i) {
                const long row = row0 + m * 16 + cr + i;
                const float v = acc[m][n][i];
                const long idx = (long)b * strideC + row * (long)ldc + col;
                if (EPI == 1) {
                    ((float*)Cout)[idx] = v * scale;
                } else if (EPI == 0) {
                    ((__hip_bfloat16*)Cout)[idx] = __float2bfloat16(v + bval);
                } else {
                    ((float*)Cout)[idx] = v + bval;
                }
            }
        }
    }
}

// ---------------------------------------------------------------------------
// out[c][r] = (bf16) in[r][c] ; LDS-tiled 32x32, block (32,8)
// in rows have stride ldIn; out rows have stride R.
// ---------------------------------------------------------------------------
template <typename TIN>
__global__ __launch_bounds__(256) void transpose_to_bf16(
    const TIN* __restrict__ in, __hip_bfloat16* __restrict__ out,
    int R, int C, int ldIn, long sIn, long sOut)
{
    __shared__ float tile[32][33];
    const int b = blockIdx.z;
    const TIN* pin = in + (long)b * sIn;
    __hip_bfloat16* pout = out + (long)b * sOut;
    const int tx = threadIdx.x, ty = threadIdx.y;
    const int c0 = blockIdx.x * 32, r0 = blockIdx.y * 32;
#pragma unroll
    for (int j = 0; j < 4; ++j)
        tile[ty + j * 8][tx] = to_f32(pin[(long)(r0 + ty + j * 8) * ldIn + c0 + tx]);
    __syncthreads();
#pragma unroll
    for (int j = 0; j < 4; ++j)
        pout[(long)(c0 + ty + j * 8) * R + r0 + tx] = __float2bfloat16(tile[tx][ty + j * 8]);
}

// ---------------------------------------------------------------------------
__global__ __launch_bounds__(256) void f32_to_bf16_vec(
    const float* __restrict__ in, __hip_bfloat16* __restrict__ out, long n4)
{
    const long i = (long)blockIdx.x * 256 + threadIdx.x;
    if (i >= n4) return;
    const float4 v = ((const float4*)in)[i];
    union { __hip_bfloat16 h[4]; ushort4 u; } cv;
    cv.h[0] = __float2bfloat16(v.x);
    cv.h[1] = __float2bfloat16(v.y);
    cv.h[2] = __float2bfloat16(v.z);
    cv.h[3] = __float2bfloat16(v.w);
    ((ushort4*)out)[i] = cv.u;
}

// ---------------------------------------------------------------------------
// Concatenated bias vector: [bq(1024) bk(1024) bv(1024) bgv(1024) bgg(1024)]
// ---------------------------------------------------------------------------
__global__ __launch_bounds__(256) void concat_bias(
    const float* __restrict__ bq, const float* __restrict__ bk, const float* __restrict__ bv,
    const float* __restrict__ bgv, const float* __restrict__ bgg, float* __restrict__ out)
{
    const int i = blockIdx.x * 256 + threadIdx.x;  // 5120 total
    float v;
    if (i < 1024) v = bq[i];
    else if (i < 2048) v = bk[i - 1024];
    else if (i < 3072) v = bv[i - 2048];
    else if (i < 4096) v = bgv[i - 3072];
    else v = bgg[i - 4096];
    out[i] = v;
}

// ---------------------------------------------------------------------------
// row softmax: one block per row of 2048 f32 scores -> bf16 probs
// ---------------------------------------------------------------------------
__global__ __launch_bounds__(256) void softmax_kernel(
    const float* __restrict__ S, __hip_bfloat16* __restrict__ P)
{
    const long row = blockIdx.x;
    const float* s = S + row * 2048;
    __hip_bfloat16* p = P + row * 2048;
    const int t = threadIdx.x;
    float v[8];
    float mx = -1e30f;
#pragma unroll
    for (int j = 0; j < 8; ++j) { v[j] = s[t + j * 256]; mx = fmaxf(mx, v[j]); }
#pragma unroll
    for (int off = 32; off; off >>= 1) mx = fmaxf(mx, __shfl_xor(mx, off));
    __shared__ float wred[4];
    __shared__ float wsum[4];
    const int w = t >> 6;
    if ((t & 63) == 0) wred[w] = mx;
    __syncthreads();
    mx = fmaxf(fmaxf(wred[0], wred[1]), fmaxf(wred[2], wred[3]));
    float sum = 0.f;
#pragma unroll
    for (int j = 0; j < 8; ++j) { v[j] = __expf(v[j] - mx); sum += v[j]; }
#pragma unroll
    for (int off = 32; off; off >>= 1) sum += __shfl_xor(sum, off);
    if ((t & 63) == 0) wsum[w] = sum;
    __syncthreads();
    sum = wsum[0] + wsum[1] + wsum[2] + wsum[3];
    const float inv = 1.0f / sum;
#pragma unroll
    for (int j = 0; j < 8; ++j) p[t + j * 256] = __float2bfloat16(v[j] * inv);
}

// ---------------------------------------------------------------------------
// y = T1 + Gv*sigmoid(Gg); out = LN(y)*gamma + beta.  One block per row.
// T1: [row][1024]; Glu: [row][2048] with val = cols 0-1023, gate = 1024-2047.
// ---------------------------------------------------------------------------
__global__ __launch_bounds__(256) void glu_ln_kernel(
    const float* __restrict__ T1, const float* __restrict__ Glu,
    const float* __restrict__ gamma, const float* __restrict__ beta, float* __restrict__ out)
{
    const long base = (long)blockIdx.x * 1024;
    const long gbase = (long)blockIdx.x * 2048;
    const int t = threadIdx.x;
    float y[4];
    float s = 0.f, ss = 0.f;
#pragma unroll
    for (int j = 0; j < 4; ++j) {
        const int i = t + j * 256;
        const float gg = Glu[gbase + 1024 + i];
        const float g = Glu[gbase + i] * (1.0f / (1.0f + __expf(-gg)));
        const float v = T1[base + i] + g;
        y[j] = v; s += v; ss += v * v;
    }
#pragma unroll
    for (int off = 32; off; off >>= 1) { s += __shfl_xor(s, off); ss += __shfl_xor(ss, off); }
    __shared__ float rs[4], rss[4];
    const int w = t >> 6;
    if ((t & 63) == 0) { rs[w] = s; rss[w] = ss; }
    __syncthreads();
    s = rs[0] + rs[1] + rs[2] + rs[3];
    ss = rss[0] + rss[1] + rss[2] + rss[3];
    const float mu = s * (1.0f / 1024.0f);
    const float var = ss * (1.0f / 1024.0f) - mu * mu;
    const float r = rsqrtf(var + 1e-5f);
#pragma unroll
    for (int j = 0; j < 4; ++j) {
        const int i = t + j * 256;
        out[base + i] = (y[j] - mu) * r * gamma[i] + beta[i];
    }
}

// ---------------------------------------------------------------------------
extern "C" void kernel_launch(void* const* d_in, const int* in_sizes, int n_in,
                              void* d_out, int out_size, void* d_ws, size_t ws_size,
                              hipStream_t stream)
{
    const int B = 4, S = 2048, D = 1024;
    const float* x    = (const float*)d_in[0];
    const float* Wq   = (const float*)d_in[1];
    const float* bq   = (const float*)d_in[2];
    const float* Wk   = (const float*)d_in[3];
    const float* bk   = (const float*)d_in[4];
    const float* Wv   = (const float*)d_in[5];
    const float* bv   = (const float*)d_in[6];
    const float* Wo   = (const float*)d_in[7];
    const float* bo   = (const float*)d_in[8];
    const float* Wgv  = (const float*)d_in[9];
    const float* bgv  = (const float*)d_in[10];
    const float* Wgg  = (const float*)d_in[11];
    const float* bgg  = (const float*)d_in[12];
    const float* gamma = (const float*)d_in[13];
    const float* beta  = (const float*)d_in[14];
    float* out = (float*)d_out;

    char* ws = (char*)d_ws;
    size_t off = 0;
    auto take = [&](size_t bytes) { char* p = ws + off; off += (bytes + 255) & ~(size_t)255; return p; };

    __hip_bfloat16* wqkv_t = (__hip_bfloat16*)take((size_t)3 * D * D * 2);  // 6 MiB  [3D][D]
    __hip_bfloat16* wo_t   = (__hip_bfloat16*)take((size_t)D * D * 2);      // 2 MiB
    __hip_bfloat16* wg_t   = (__hip_bfloat16*)take((size_t)2 * D * D * 2);  // 4 MiB  [2D][D]
    float*          bcat   = (float*)take((size_t)5 * D * 4);               // bqkv(3072) + bglu(2048)
    __hip_bfloat16* xb     = (__hip_bfloat16*)take((size_t)B * S * D * 2);  // 16 MiB
    __hip_bfloat16* QKVb   = (__hip_bfloat16*)take((size_t)B * S * 3 * D * 2); // 48 MiB [B*S][3D]
    __hip_bfloat16* Vtb    = (__hip_bfloat16*)take((size_t)B * S * D * 2);  // 16 MiB [B][D][S]
    float*          scores = (float*)take((size_t)B * S * S * 4);           // 64 MiB (reused as Glu out)
    __hip_bfloat16* Pb     = (__hip_bfloat16*)take((size_t)B * S * S * 2);  // 32 MiB
    __hip_bfloat16* Oatt   = (__hip_bfloat16*)take((size_t)B * S * D * 2);  // 16 MiB
    float*          T1     = (float*)take((size_t)B * S * D * 4);           // 32 MiB
    float* Glu = scores;    // [8192][2048] f32, reuse (scores dead after softmax)

    const long SD = (long)S * D, SS = (long)S * S, S3D = (long)S * 3 * D;
    const float att_scale = 0.03125f;  // 1/sqrt(1024)
    const __hip_bfloat16* Qb = QKVb;
    const __hip_bfloat16* Kb = QKVb + D;
    const __hip_bfloat16* Vb = QKVb + 2 * D;

    // 1. casts / weight transposes (Wt[e][d] = W[d][e] so every GEMM is bt-format)
    f32_to_bf16_vec<<<dim3((unsigned)((long)B * S * D / 4 / 256)), dim3(256), 0, stream>>>(x, xb, (long)B * S * D / 4);
    transpose_to_bf16<float><<<dim3(D / 32, D / 32, 1), dim3(32, 8), 0, stream>>>(Wq,  wqkv_t,           D, D, D, 0, 0);
    transpose_to_bf16<float><<<dim3(D / 32, D / 32, 1), dim3(32, 8), 0, stream>>>(Wk,  wqkv_t + D * D,   D, D, D, 0, 0);
    transpose_to_bf16<float><<<dim3(D / 32, D / 32, 1), dim3(32, 8), 0, stream>>>(Wv,  wqkv_t + 2 * D * D, D, D, D, 0, 0);
    transpose_to_bf16<float><<<dim3(D / 32, D / 32, 1), dim3(32, 8), 0, stream>>>(Wo,  wo_t,             D, D, D, 0, 0);
    transpose_to_bf16<float><<<dim3(D / 32, D / 32, 1), dim3(32, 8), 0, stream>>>(Wgv, wg_t,             D, D, D, 0, 0);
    transpose_to_bf16<float><<<dim3(D / 32, D / 32, 1), dim3(32, 8), 0, stream>>>(Wgg, wg_t + D * D,     D, D, D, 0, 0);
    concat_bias<<<dim3(20), dim3(256), 0, stream>>>(bq, bk, bv, bgv, bgg, bcat);

    // 2. fused QKV projection: [8192][1024] x [3072][1024]^T -> [8192][3072] bf16
    gemm_bt<0><<<dim3(B * S / 128, 3 * D / 128, 1), dim3(256), 0, stream>>>(
        xb, wqkv_t, QKVb, bcat, 1.f, 3 * D, D, D, D, 3 * D, 0, 0, 0);

    // 3. scores = scale * Q K^T  (f32), per batch
    gemm_bt<1><<<dim3(S / 128, S / 128, B), dim3(256), 0, stream>>>(
        Qb, Kb, scores, nullptr, att_scale, S, D, 3 * D, 3 * D, S, S3D, S3D, SS);

    // 4. row softmax -> bf16 P
    softmax_kernel<<<dim3(B * S), dim3(256), 0, stream>>>(scores, Pb);

    // 5. V^T per batch, then Oatt = P @ V
    transpose_to_bf16<__hip_bfloat16><<<dim3(D / 32, S / 32, B), dim3(32, 8), 0, stream>>>(
        Vb, Vtb, S, D, 3 * D, S3D, SD);
    gemm_bt<0><<<dim3(S / 128, D / 128, B), dim3(256), 0, stream>>>(
        Pb, Vtb, Oatt, nullptr, 1.f, D, S, S, S, D, SS, SD, SD);

    // 6. T1 = Oatt @ Wo + bo (f32)
    gemm_bt<2><<<dim3(B * S / 128, D / 128, 1), dim3(256), 0, stream>>>(
        Oatt, wo_t, T1, bo, 1.f, D, D, D, D, D, 0, 0, 0);

    // 7. fused GLU gemm: Q[8192][1024] x [2048][1024]^T -> [8192][2048] f32
    gemm_bt<2><<<dim3(B * S / 128, 2 * D / 128, 1), dim3(256), 0, stream>>>(
        Qb, wg_t, Glu, bcat + 3 * D, 1.f, 2 * D, D, 3 * D, D, 2 * D, 0, 0, 0);

    // 8. y = T1 + Gval*sigmoid(Ggate); out = LayerNorm(y)*gamma+beta
    glu_ln_kernel<<<dim3(B * S), dim3(256), 0, stream>>>(T1, Glu, gamma, beta, out);
}

// Round 5
// 291.433 us; speedup vs baseline: 1.3138x; 1.2421x over previous
//
#include <hip/hip_runtime.h>
#include <hip/hip_bf16.h>
#include <cstdint>

// ---------------------------------------------------------------------------
// SelfAttention fused block: B=4, S=2048, D=1024, fp32 in/out.
// R2 (resubmit after infra failure): all GEMMs on a 256x256/BK=64 8-wave
// kernel with 4-phase K-tiles, counted vmcnt(4) waits (loads span barriers),
// raw s_barrier, setprio, LDS XOR-swizzle (pre-swizzled global source +
// swizzled ds_read).
// Wait-correctness argument (per-tile stage order A0,B0,B1,A1; phase needs
// A0B0 / B1 / A1 / -): vmcnt(4) pre-barrier at phase ends 1,2,4 guarantees
// the half-tile needed next phase is collectively complete.
// ---------------------------------------------------------------------------

typedef __bf16 bf16x8 __attribute__((ext_vector_type(8)));
typedef float f32x4 __attribute__((ext_vector_type(4)));

#define SYNC() do { asm volatile("" ::: "memory"); __builtin_amdgcn_s_barrier(); asm volatile("" ::: "memory"); } while (0)
#define WAITV(n) asm volatile("s_waitcnt vmcnt(" #n ")" ::: "memory")

__device__ __forceinline__ void gload_lds16(const void* g, void* l) {
    __builtin_amdgcn_global_load_lds(
        (__attribute__((address_space(1))) void*)(uintptr_t)g,
        (__attribute__((address_space(3))) void*)(uintptr_t)l,
        16, 0, 0);
}

__device__ __forceinline__ float to_f32(float x) { return x; }
__device__ __forceinline__ float to_f32(__hip_bfloat16 x) { return __bfloat162float(x); }

// ---------------------------------------------------------------------------
// gemm256: C[m,n] = sum_k A[m,k] * Bt[n,k]
// Tile 256x256, BK=64, 512 threads = 8 waves (wm=wid&1 -> 2 row-strips of 64,
// wn=wid>>1 -> 4 col-strips of 32; each wave covers both A-halves and both
// B-halves via quadrants, enabling per-half pipelined waits).
// LDS 128 KiB: [buf(2)][op(2: A,B)][half(2)][128 rows][64 cols] bf16.
// EPI 0: bf16 out = acc + bias ; EPI 1: f32 out = acc*scale ; EPI 2: f32 out = acc + bias
// ---------------------------------------------------------------------------
template <int EPI>
__global__ __launch_bounds__(512, 1) void gemm256(
    const __hip_bfloat16* __restrict__ A, const __hip_bfloat16* __restrict__ Bt,
    void* __restrict__ Cout, const float* __restrict__ bias, float scale,
    int K, int lda, int ldb, int ldc,
    long strideA, long strideB, long strideC)
{
    __shared__ __align__(16) char smem[131072];

    const int b = blockIdx.z;
    const int tid = threadIdx.x;
    const int lane = tid & 63;
    const int wm = (tid >> 6) & 1;        // row strip (64 rows within each A-half)
    const int wn = (tid >> 6) >> 1;       // col strip (32 cols within each B-half)

    const __hip_bfloat16* gA = A + (long)b * strideA + (long)blockIdx.x * 256 * lda;
    const __hip_bfloat16* gB = Bt + (long)b * strideB + (long)blockIdx.y * 256 * ldb;

    // staging geometry: 2 chunks/thread per half-tile (128 rows x 128 B)
    const int r0 = tid >> 3;                 // rows 0..63
    const int s0 = (tid & 7) ^ (r0 & 7);     // inverse-swizzled 16B slot
    const int r1 = r0 + 64;                  // rows 64..127
    const int s1 = (tid & 7) ^ (r1 & 7);

    // STAGE(buf, isB, half, kt): issue 2 global_load_lds (linear LDS dst)
#define STAGE(buf, isB, half, kt)                                                        \
    do {                                                                                 \
        const __hip_bfloat16* g_ = (isB) ? gB : gA;                                      \
        const int ld_ = (isB) ? ldb : lda;                                               \
        char* l_ = smem + (buf) * 65536 + (isB) * 32768 + (half) * 16384;                \
        gload_lds16(g_ + (long)((half) * 128 + r0) * ld_ + (kt) * 64 + s0 * 8, l_ + tid * 16);        \
        gload_lds16(g_ + (long)((half) * 128 + r1) * ld_ + (kt) * 64 + s1 * 8, l_ + 8192 + tid * 16); \
    } while (0)

    const int fr = lane & 15;            // fragment row/col
    const int kg = lane >> 4;            // k-group (8 elems)

    // fragment loads (swizzled to match staging pre-swizzle)
#define LDA_(dst, buf, mh, mi, kk)                                                       \
    do {                                                                                 \
        const int lr_ = wm * 64 + (mi) * 16 + fr;                                        \
        const int sl_ = ((kk) * 4 + kg) ^ (lr_ & 7);                                     \
        dst = *(const bf16x8*)(smem + (buf) * 65536 + (mh) * 16384 + lr_ * 128 + sl_ * 16); \
    } while (0)
#define LDB_(dst, buf, nh, ni, kk)                                                       \
    do {                                                                                 \
        const int lr_ = wn * 32 + (ni) * 16 + fr;                                        \
        const int sl_ = ((kk) * 4 + kg) ^ (lr_ & 7);                                     \
        dst = *(const bf16x8*)(smem + (buf) * 65536 + 32768 + (nh) * 16384 + lr_ * 128 + sl_ * 16); \
    } while (0)

    f32x4 acc[2][2][4][2];
#pragma unroll
    for (int mh = 0; mh < 2; ++mh)
#pragma unroll
        for (int nh = 0; nh < 2; ++nh)
#pragma unroll
            for (int mi = 0; mi < 4; ++mi)
#pragma unroll
                for (int ni = 0; ni < 2; ++ni) acc[mh][nh][mi][ni] = {0.f, 0.f, 0.f, 0.f};

    bf16x8 av[4][2], bv[2][2];

#define MFMA_QUAD(mh, nh)                                                                \
    do {                                                                                 \
        __builtin_amdgcn_s_setprio(1);                                                   \
        _Pragma("unroll")                                                                \
        for (int mi = 0; mi < 4; ++mi)                                                   \
            _Pragma("unroll")                                                            \
            for (int ni = 0; ni < 2; ++ni)                                               \
                _Pragma("unroll")                                                        \
                for (int kk = 0; kk < 2; ++kk)                                           \
                    acc[mh][nh][mi][ni] = __builtin_amdgcn_mfma_f32_16x16x32_bf16(       \
                        av[mi][kk], bv[ni][kk], acc[mh][nh][mi][ni], 0, 0, 0);           \
        __builtin_amdgcn_s_setprio(0);                                                   \
    } while (0)

    const int NT = K >> 6;   // K-tiles of 64 (NT >= 2 for all our shapes)

    // prologue: stage tile 0 in wait-order A0,B0,B1,A1
    STAGE(0, 0, 0, 0);
    STAGE(0, 1, 0, 0);
    STAGE(0, 1, 1, 0);
    STAGE(0, 0, 1, 0);
    WAITV(4);   // A0,B0 of tile0 done collectively after barrier
    SYNC();

    for (int t = 0; t < NT - 1; ++t) {
        const int c = t & 1;
        // P1: quad(0,0) — reads A-half0, B-half0; stage A0 of t+1
#pragma unroll
        for (int mi = 0; mi < 4; ++mi) { LDA_(av[mi][0], c, 0, mi, 0); LDA_(av[mi][1], c, 0, mi, 1); }
#pragma unroll
        for (int ni = 0; ni < 2; ++ni) { LDB_(bv[ni][0], c, 0, ni, 0); LDB_(bv[ni][1], c, 0, ni, 1); }
        STAGE(c ^ 1, 0, 0, t + 1);
        MFMA_QUAD(0, 0);
        WAITV(4);   // B1 of tile t done (newest 4: A1[t], A0[t+1])
        SYNC();
        // P2: quad(0,1) — reads B-half1; stage B0 of t+1
#pragma unroll
        for (int ni = 0; ni < 2; ++ni) { LDB_(bv[ni][0], c, 1, ni, 0); LDB_(bv[ni][1], c, 1, ni, 1); }
        STAGE(c ^ 1, 1, 0, t + 1);
        MFMA_QUAD(0, 1);
        WAITV(4);   // A1 of tile t done (newest 4: A0[t+1], B0[t+1])
        SYNC();
        // P3: quad(1,1) — reads A-half1; stage B1 of t+1 (no wait/barrier needed)
#pragma unroll
        for (int mi = 0; mi < 4; ++mi) { LDA_(av[mi][0], c, 1, mi, 0); LDA_(av[mi][1], c, 1, mi, 1); }
        STAGE(c ^ 1, 1, 1, t + 1);
        MFMA_QUAD(1, 1);
        SYNC();
        // P4: quad(1,0) — re-reads B-half0; stage A1 of t+1
#pragma unroll
        for (int ni = 0; ni < 2; ++ni) { LDB_(bv[ni][0], c, 0, ni, 0); LDB_(bv[ni][1], c, 0, ni, 1); }
        STAGE(c ^ 1, 0, 1, t + 1);
        MFMA_QUAD(1, 0);
        WAITV(4);   // A0,B0 of tile t+1 done (newest 4: B1[t+1], A1[t+1])
        SYNC();
    }

    // peeled last tile (no stages outstanding ordinals shift)
    {
        const int c = (NT - 1) & 1;
#pragma unroll
        for (int mi = 0; mi < 4; ++mi) { LDA_(av[mi][0], c, 0, mi, 0); LDA_(av[mi][1], c, 0, mi, 1); }
#pragma unroll
        for (int ni = 0; ni < 2; ++ni) { LDB_(bv[ni][0], c, 0, ni, 0); LDB_(bv[ni][1], c, 0, ni, 1); }
        MFMA_QUAD(0, 0);
        WAITV(2);   // B1 of last tile done (newest 2: A1[last])
        SYNC();
#pragma unroll
        for (int ni = 0; ni < 2; ++ni) { LDB_(bv[ni][0], c, 1, ni, 0); LDB_(bv[ni][1], c, 1, ni, 1); }
        MFMA_QUAD(0, 1);
        WAITV(0);   // A1 of last tile done
        SYNC();
#pragma unroll
        for (int mi = 0; mi < 4; ++mi) { LDA_(av[mi][0], c, 1, mi, 0); LDA_(av[mi][1], c, 1, mi, 1); }
        MFMA_QUAD(1, 1);
#pragma unroll
        for (int ni = 0; ni < 2; ++ni) { LDB_(bv[ni][0], c, 0, ni, 0); LDB_(bv[ni][1], c, 0, ni, 1); }
        MFMA_QUAD(1, 0);
    }

    // epilogue: C/D layout per 16x16 frag: col = lane&15, row = (lane>>4)*4 + i
    const long row0 = (long)blockIdx.x * 256 + wm * 64 + (lane >> 4) * 4;
    const long col0 = (long)blockIdx.y * 256 + wn * 32 + (lane & 15);
#pragma unroll
    for (int mh = 0; mh < 2; ++mh) {
#pragma unroll
        for (int nh = 0; nh < 2; ++nh) {
#pragma unroll
            for (int ni = 0; ni < 2; ++ni) {
                const long col = col0 + nh * 128 + ni * 16;
                const float bval = (EPI != 1 && bias != nullptr) ? bias[col] : 0.f;
#pragma unroll
                for (int mi = 0; mi < 4; ++mi) {
#pragma unroll
                    for (int i = 0; i < 4; ++i) {
                        const long row = row0 + mh * 128 + mi * 16 + i;
                        const float v = acc[mh][nh][mi][ni][i];
                        const long idx = (long)b * strideC + row * (long)ldc + col;
                        if (EPI == 1) ((float*)Cout)[idx] = v * scale;
                        else if (EPI == 0) ((__hip_bfloat16*)Cout)[idx] = __float2bfloat16(v + bval);
                        else ((float*)Cout)[idx] = v + bval;
                    }
                }
            }
        }
    }
#undef STAGE
#undef LDA_
#undef LDB_
#undef MFMA_QUAD
}

// ---------------------------------------------------------------------------
// out[c][r] = (bf16) in[r][c] ; LDS-tiled 32x32, block (32,8)
// ---------------------------------------------------------------------------
template <typename TIN>
__global__ __launch_bounds__(256) void transpose_to_bf16(
    const TIN* __restrict__ in, __hip_bfloat16* __restrict__ out,
    int R, int C, int ldIn, long sIn, long sOut)
{
    __shared__ float tile[32][33];
    const int b = blockIdx.z;
    const TIN* pin = in + (long)b * sIn;
    __hip_bfloat16* pout = out + (long)b * sOut;
    const int tx = threadIdx.x, ty = threadIdx.y;
    const int c0 = blockIdx.x * 32, r0 = blockIdx.y * 32;
#pragma unroll
    for (int j = 0; j < 4; ++j)
        tile[ty + j * 8][tx] = to_f32(pin[(long)(r0 + ty + j * 8) * ldIn + c0 + tx]);
    __syncthreads();
#pragma unroll
    for (int j = 0; j < 4; ++j)
        pout[(long)(c0 + ty + j * 8) * R + r0 + tx] = __float2bfloat16(tile[tx][ty + j * 8]);
}

// ---------------------------------------------------------------------------
__global__ __launch_bounds__(256) void f32_to_bf16_vec(
    const float* __restrict__ in, __hip_bfloat16* __restrict__ out, long n4)
{
    const long i = (long)blockIdx.x * 256 + threadIdx.x;
    if (i >= n4) return;
    const float4 v = ((const float4*)in)[i];
    union { __hip_bfloat16 h[4]; ushort4 u; } cv;
    cv.h[0] = __float2bfloat16(v.x);
    cv.h[1] = __float2bfloat16(v.y);
    cv.h[2] = __float2bfloat16(v.z);
    cv.h[3] = __float2bfloat16(v.w);
    ((ushort4*)out)[i] = cv.u;
}

// ---------------------------------------------------------------------------
__global__ __launch_bounds__(256) void concat_bias(
    const float* __restrict__ bq, const float* __restrict__ bk, const float* __restrict__ bv,
    const float* __restrict__ bgv, const float* __restrict__ bgg, float* __restrict__ out)
{
    const int i = blockIdx.x * 256 + threadIdx.x;  // 5120 total
    float v;
    if (i < 1024) v = bq[i];
    else if (i < 2048) v = bk[i - 1024];
    else if (i < 3072) v = bv[i - 2048];
    else if (i < 4096) v = bgv[i - 3072];
    else v = bgg[i - 4096];
    out[i] = v;
}

// ---------------------------------------------------------------------------
// row softmax: one block per row of 2048 f32 scores -> bf16 probs
// ---------------------------------------------------------------------------
__global__ __launch_bounds__(256) void softmax_kernel(
    const float* __restrict__ S, __hip_bfloat16* __restrict__ P)
{
    const long row = blockIdx.x;
    const float* s = S + row * 2048;
    __hip_bfloat16* p = P + row * 2048;
    const int t = threadIdx.x;
    float v[8];
    float mx = -1e30f;
#pragma unroll
    for (int j = 0; j < 8; ++j) { v[j] = s[t + j * 256]; mx = fmaxf(mx, v[j]); }
#pragma unroll
    for (int off = 32; off; off >>= 1) mx = fmaxf(mx, __shfl_xor(mx, off));
    __shared__ float wred[4];
    __shared__ float wsum[4];
    const int w = t >> 6;
    if ((t & 63) == 0) wred[w] = mx;
    __syncthreads();
    mx = fmaxf(fmaxf(wred[0], wred[1]), fmaxf(wred[2], wred[3]));
    float sum = 0.f;
#pragma unroll
    for (int j = 0; j < 8; ++j) { v[j] = __expf(v[j] - mx); sum += v[j]; }
#pragma unroll
    for (int off = 32; off; off >>= 1) sum += __shfl_xor(sum, off);
    if ((t & 63) == 0) wsum[w] = sum;
    __syncthreads();
    sum = wsum[0] + wsum[1] + wsum[2] + wsum[3];
    const float inv = 1.0f / sum;
#pragma unroll
    for (int j = 0; j < 8; ++j) p[t + j * 256] = __float2bfloat16(v[j] * inv);
}

// ---------------------------------------------------------------------------
// y = T1 + Gv*sigmoid(Gg); out = LN(y)*gamma + beta.  One block per row.
// ---------------------------------------------------------------------------
__global__ __launch_bounds__(256) void glu_ln_kernel(
    const float* __restrict__ T1, const float* __restrict__ Glu,
    const float* __restrict__ gamma, const float* __restrict__ beta, float* __restrict__ out)
{
    const long base = (long)blockIdx.x * 1024;
    const long gbase = (long)blockIdx.x * 2048;
    const int t = threadIdx.x;
    float y[4];
    float s = 0.f, ss = 0.f;
#pragma unroll
    for (int j = 0; j < 4; ++j) {
        const int i = t + j * 256;
        const float gg = Glu[gbase + 1024 + i];
        const float g = Glu[gbase + i] * (1.0f / (1.0f + __expf(-gg)));
        const float v = T1[base + i] + g;
        y[j] = v; s += v; ss += v * v;
    }
#pragma unroll
    for (int off = 32; off; off >>= 1) { s += __shfl_xor(s, off); ss += __shfl_xor(ss, off); }
    __shared__ float rs[4], rss[4];
    const int w = t >> 6;
    if ((t & 63) == 0) { rs[w] = s; rss[w] = ss; }
    __syncthreads();
    s = rs[0] + rs[1] + rs[2] + rs[3];
    ss = rss[0] + rss[1] + rss[2] + rss[3];
    const float mu = s * (1.0f / 1024.0f);
    const float var = ss * (1.0f / 1024.0f) - mu * mu;
    const float r = rsqrtf(var + 1e-5f);
#pragma unroll
    for (int j = 0; j < 4; ++j) {
        const int i = t + j * 256;
        out[base + i] = (y[j] - mu) * r * gamma[i] + beta[i];
    }
}

// ---------------------------------------------------------------------------
extern "C" void kernel_launch(void* const* d_in, const int* in_sizes, int n_in,
                              void* d_out, int out_size, void* d_ws, size_t ws_size,
                              hipStream_t stream)
{
    const int B = 4, S = 2048, D = 1024;
    const float* x    = (const float*)d_in[0];
    const float* Wq   = (const float*)d_in[1];
    const float* bq   = (const float*)d_in[2];
    const float* Wk   = (const float*)d_in[3];
    const float* bk   = (const float*)d_in[4];
    const float* Wv   = (const float*)d_in[5];
    const float* bv   = (const float*)d_in[6];
    const float* Wo   = (const float*)d_in[7];
    const float* bo   = (const float*)d_in[8];
    const float* Wgv  = (const float*)d_in[9];
    const float* bgv  = (const float*)d_in[10];
    const float* Wgg  = (const float*)d_in[11];
    const float* bgg  = (const float*)d_in[12];
    const float* gamma = (const float*)d_in[13];
    const float* beta  = (const float*)d_in[14];
    float* out = (float*)d_out;

    char* ws = (char*)d_ws;
    size_t off = 0;
    auto take = [&](size_t bytes) { char* p = ws + off; off += (bytes + 255) & ~(size_t)255; return p; };

    __hip_bfloat16* wqkv_t = (__hip_bfloat16*)take((size_t)3 * D * D * 2);  // [3D][D]
    __hip_bfloat16* wo_t   = (__hip_bfloat16*)take((size_t)D * D * 2);
    __hip_bfloat16* wg_t   = (__hip_bfloat16*)take((size_t)2 * D * D * 2);  // [2D][D]
    float*          bcat   = (float*)take((size_t)5 * D * 4);
    __hip_bfloat16* xb     = (__hip_bfloat16*)take((size_t)B * S * D * 2);
    __hip_bfloat16* QKVb   = (__hip_bfloat16*)take((size_t)B * S * 3 * D * 2); // [B*S][3D]
    __hip_bfloat16* Vtb    = (__hip_bfloat16*)take((size_t)B * S * D * 2);  // [B][D][S]
    float*          scores = (float*)take((size_t)B * S * S * 4);           // reused as Glu out
    __hip_bfloat16* Pb     = (__hip_bfloat16*)take((size_t)B * S * S * 2);
    __hip_bfloat16* Oatt   = (__hip_bfloat16*)take((size_t)B * S * D * 2);
    float*          T1     = (float*)take((size_t)B * S * D * 4);
    float* Glu = scores;    // [8192][2048] f32 (scores dead after softmax)

    const long SD = (long)S * D, SS = (long)S * S, S3D = (long)S * 3 * D;
    const float att_scale = 0.03125f;  // 1/sqrt(1024)
    const __hip_bfloat16* Qb = QKVb;
    const __hip_bfloat16* Kb = QKVb + D;
    const __hip_bfloat16* Vb = QKVb + 2 * D;

    // 1. casts / weight transposes
    f32_to_bf16_vec<<<dim3((unsigned)((long)B * S * D / 4 / 256)), dim3(256), 0, stream>>>(x, xb, (long)B * S * D / 4);
    transpose_to_bf16<float><<<dim3(D / 32, D / 32, 1), dim3(32, 8), 0, stream>>>(Wq,  wqkv_t,             D, D, D, 0, 0);
    transpose_to_bf16<float><<<dim3(D / 32, D / 32, 1), dim3(32, 8), 0, stream>>>(Wk,  wqkv_t + D * D,     D, D, D, 0, 0);
    transpose_to_bf16<float><<<dim3(D / 32, D / 32, 1), dim3(32, 8), 0, stream>>>(Wv,  wqkv_t + 2 * D * D, D, D, D, 0, 0);
    transpose_to_bf16<float><<<dim3(D / 32, D / 32, 1), dim3(32, 8), 0, stream>>>(Wo,  wo_t,               D, D, D, 0, 0);
    transpose_to_bf16<float><<<dim3(D / 32, D / 32, 1), dim3(32, 8), 0, stream>>>(Wgv, wg_t,               D, D, D, 0, 0);
    transpose_to_bf16<float><<<dim3(D / 32, D / 32, 1), dim3(32, 8), 0, stream>>>(Wgg, wg_t + D * D,       D, D, D, 0, 0);
    concat_bias<<<dim3(20), dim3(256), 0, stream>>>(bq, bk, bv, bgv, bgg, bcat);

    // 2. fused QKV projection: [8192][1024] x [3072][1024]^T -> [8192][3072] bf16
    gemm256<0><<<dim3(B * S / 256, 3 * D / 256, 1), dim3(512), 0, stream>>>(
        xb, wqkv_t, QKVb, bcat, 1.f, D, D, D, 3 * D, 0, 0, 0);

    // 3. scores = scale * Q K^T  (f32), per batch
    gemm256<1><<<dim3(S / 256, S / 256, B), dim3(512), 0, stream>>>(
        Qb, Kb, scores, nullptr, att_scale, D, 3 * D, 3 * D, S, S3D, S3D, SS);

    // 4. row softmax -> bf16 P
    softmax_kernel<<<dim3(B * S), dim3(256), 0, stream>>>(scores, Pb);

    // 5. V^T per batch, then Oatt = P @ V
    transpose_to_bf16<__hip_bfloat16><<<dim3(D / 32, S / 32, B), dim3(32, 8), 0, stream>>>(
        Vb, Vtb, S, D, 3 * D, S3D, SD);
    gemm256<0><<<dim3(S / 256, D / 256, B), dim3(512), 0, stream>>>(
        Pb, Vtb, Oatt, nullptr, 1.f, S, S, S, D, SS, SD, SD);

    // 6. T1 = Oatt @ Wo + bo (f32)
    gemm256<2><<<dim3(B * S / 256, D / 256, 1), dim3(512), 0, stream>>>(
        Oatt, wo_t, T1, bo, 1.f, D, D, D, D, 0, 0, 0);

    // 7. fused GLU gemm: Q[8192][1024] x [2048][1024]^T -> [8192][2048] f32
    gemm256<2><<<dim3(B * S / 256, 2 * D / 256, 1), dim3(512), 0, stream>>>(
        Qb, wg_t, Glu, bcat + 3 * D, 1.f, D, 3 * D, D, 2 * D, 0, 0, 0);

    // 8. y = T1 + Gval*sigmoid(Ggate); out = LayerNorm(y)*gamma+beta
    glu_ln_kernel<<<dim3(B * S), dim3(256), 0, stream>>>(T1, Glu, gamma, beta, out);
}

// Round 6
// 263.243 us; speedup vs baseline: 1.4545x; 1.1071x over previous
//
#include <hip/hip_runtime.h>
#include <hip/hip_bf16.h>
#include <cstdint>

// ---------------------------------------------------------------------------
// SelfAttention fused block: B=4, S=2048, D=1024, fp32 in/out.
// R3: grid-quantization fixes. New gemm_tn128 (256x128, BK=64, TRIPLE-buffer
// LDS, one barrier + counted vmcnt(6) per K-tile) for QKV (768 blk), PV (256),
// and a fused Wo+GLU dispatch (768 blk, per-column-tile A select). Scores stay
// on the 256^2 4-phase kernel (256 blk) but output bf16. Epilogue kernels
// vectorized; Wo/GLU outputs bf16 into one [8192][3072] buffer.
// ---------------------------------------------------------------------------

typedef __bf16 bf16x8 __attribute__((ext_vector_type(8)));
typedef __bf16 bf16x4 __attribute__((ext_vector_type(4)));
typedef float f32x4 __attribute__((ext_vector_type(4)));

#define SYNC() do { asm volatile("" ::: "memory"); __builtin_amdgcn_s_barrier(); asm volatile("" ::: "memory"); } while (0)
#define WAITV(n) asm volatile("s_waitcnt vmcnt(" #n ")" ::: "memory")

__device__ __forceinline__ void gload_lds16(const void* g, void* l) {
    __builtin_amdgcn_global_load_lds(
        (__attribute__((address_space(1))) void*)(uintptr_t)g,
        (__attribute__((address_space(3))) void*)(uintptr_t)l,
        16, 0, 0);
}

__device__ __forceinline__ float to_f32(float x) { return x; }
__device__ __forceinline__ float to_f32(__hip_bfloat16 x) { return __bfloat162float(x); }

// ---------------------------------------------------------------------------
// gemm_tn128: C[m,n] = sum_k A[m,k]*Bt[n,k], tile 256x128, BK=64, 8 waves
// (wm=wid&3 -> 4 row strips of 64; wn=wid>>2 -> 2 col strips of 64).
// Per wave: 4x4 frags of 16x16x32, 32 MFMA / K-tile.
// LDS: 3 bufs x 48 KiB  [A 256x64 | B 128x64] bf16, row-major, 16B-slot XOR
// swizzle (slot ^= row&7) applied on the GLOBAL source at staging and on the
// ds_read address (LDS linear, rule #21).
// Pipeline: stage tile t+2 during tile t; end-of-tile WAITV(6) completes
// exactly tile t+1's 6 loads (12 outstanding -> 6). One barrier per K-tile.
// A-select: column-tiles with blockIdx.y*128 >= nsplit read A2/lda2 (fused
// Wo+GLU). Output bf16 + optional bias.
// ---------------------------------------------------------------------------
__global__ __launch_bounds__(512, 1) void gemm_tn128(
    const __hip_bfloat16* __restrict__ A1, int lda1,
    const __hip_bfloat16* __restrict__ A2, int lda2, int nsplit,
    const __hip_bfloat16* __restrict__ Bt,
    __hip_bfloat16* __restrict__ Cout, const float* __restrict__ bias,
    int K, int ldb, int ldc,
    long strideA, long strideB, long strideC)
{
    __shared__ __align__(16) char smem[147456];   // 3 x 49152

    const int b = blockIdx.z;
    const int tid = threadIdx.x;
    const int lane = tid & 63;
    const int wid = tid >> 6;
    const int wm = wid & 3;        // row strip (64)
    const int wn = wid >> 2;       // col strip (64)

    const bool sel2 = ((int)blockIdx.y * 128) >= nsplit;
    const __hip_bfloat16* A = sel2 ? A2 : A1;
    const int lda = sel2 ? lda2 : lda1;

    const __hip_bfloat16* gA = A + (long)b * strideA + (long)blockIdx.x * 256 * lda;
    const __hip_bfloat16* gB = Bt + (long)b * strideB + (long)blockIdx.y * 128 * ldb;

    const int r0 = tid >> 3, r1 = r0 + 64;          // rows within a 128-row region
    const int s0 = (tid & 7) ^ (r0 & 7);            // inverse-swizzled source slot
    const int s1 = (tid & 7) ^ (r1 & 7);

#define STG_A(base_, h_, kt_)                                                                              \
    do {                                                                                                   \
        gload_lds16(gA + (long)((h_) * 128 + r0) * lda + (kt_) * 64 + s0 * 8, (base_) + (h_) * 16384 + tid * 16);        \
        gload_lds16(gA + (long)((h_) * 128 + r1) * lda + (kt_) * 64 + s1 * 8, (base_) + (h_) * 16384 + 8192 + tid * 16); \
    } while (0)
#define STG_B(base_, kt_)                                                                                  \
    do {                                                                                                   \
        gload_lds16(gB + (long)r0 * ldb + (kt_) * 64 + s0 * 8, (base_) + 32768 + tid * 16);                \
        gload_lds16(gB + (long)r1 * ldb + (kt_) * 64 + s1 * 8, (base_) + 32768 + 8192 + tid * 16);         \
    } while (0)

    const int fr = lane & 15;
    const int kg = lane >> 4;

#define LD_A(dst, base_, mi_, kk_)                                                        \
    do {                                                                                  \
        const int row_ = wm * 64 + (mi_) * 16 + fr;                                       \
        const int sl_ = ((kk_) * 4 + kg) ^ (row_ & 7);                                    \
        dst = *(const bf16x8*)((base_) + row_ * 128 + sl_ * 16);                          \
    } while (0)
#define LD_B(dst, base_, ni_, kk_)                                                        \
    do {                                                                                  \
        const int row_ = wn * 64 + (ni_) * 16 + fr;                                       \
        const int sl_ = ((kk_) * 4 + kg) ^ (row_ & 7);                                    \
        dst = *(const bf16x8*)((base_) + 32768 + row_ * 128 + sl_ * 16);                  \
    } while (0)

    f32x4 acc[4][4];
#pragma unroll
    for (int mi = 0; mi < 4; ++mi)
#pragma unroll
        for (int ni = 0; ni < 4; ++ni) acc[mi][ni] = {0.f, 0.f, 0.f, 0.f};

    const int NT = K >> 6;   // >= 3 for all uses (16 or 32)

    // prologue: tiles 0,1 -> bufs 0,1
    STG_A(smem, 0, 0); STG_A(smem, 1, 0); STG_B(smem, 0);
    STG_A(smem + 49152, 0, 1); STG_A(smem + 49152, 1, 1); STG_B(smem + 49152, 1);
    WAITV(6);   // tile 0's 6 loads done collectively after barrier
    SYNC();

    int bi = 0;
    for (int t = 0; t < NT; ++t) {
        char* base = smem + bi * 49152;
        if (t + 2 < NT) {
            int bs = bi + 2; if (bs >= 3) bs -= 3;
            char* sb = smem + bs * 49152;
            STG_A(sb, 0, t + 2); STG_A(sb, 1, t + 2); STG_B(sb, t + 2);
        }
        bf16x8 av[4], bv[4];
#pragma unroll
        for (int kk = 0; kk < 2; ++kk) {
#pragma unroll
            for (int mi = 0; mi < 4; ++mi) LD_A(av[mi], base, mi, kk);
#pragma unroll
            for (int ni = 0; ni < 4; ++ni) LD_B(bv[ni], base, ni, kk);
            __builtin_amdgcn_s_setprio(1);
#pragma unroll
            for (int mi = 0; mi < 4; ++mi)
#pragma unroll
                for (int ni = 0; ni < 4; ++ni)
                    acc[mi][ni] = __builtin_amdgcn_mfma_f32_16x16x32_bf16(av[mi], bv[ni], acc[mi][ni], 0, 0, 0);
            __builtin_amdgcn_s_setprio(0);
        }
        if (t + 2 < NT) { WAITV(6); SYNC(); }          // completes tile t+1's loads
        else if (t + 1 < NT) { WAITV(0); SYNC(); }     // last prefetched tile
        bi = (bi + 1 == 3) ? 0 : bi + 1;
    }

    // epilogue: frag C/D layout: col=lane&15, row=(lane>>4)*4+i
    const long row0 = (long)blockIdx.x * 256 + wm * 64 + (lane >> 4) * 4;
    const long col0 = (long)blockIdx.y * 128 + wn * 64 + (lane & 15);
#pragma unroll
    for (int ni = 0; ni < 4; ++ni) {
        const long col = col0 + ni * 16;
        const float bval = (bias != nullptr) ? bias[col] : 0.f;
#pragma unroll
        for (int mi = 0; mi < 4; ++mi) {
#pragma unroll
            for (int i = 0; i < 4; ++i) {
                const long row = row0 + mi * 16 + i;
                Cout[(long)b * strideC + row * (long)ldc + col] = __float2bfloat16(acc[mi][ni][i] + bval);
            }
        }
    }
#undef STG_A
#undef STG_B
#undef LD_A
#undef LD_B
}

// ---------------------------------------------------------------------------
// gemm256 (kept for scores): 256x256/BK=64, 4-phase, counted vmcnt(4).
// EPI 1: bf16 out = acc*scale.
// ---------------------------------------------------------------------------
template <int EPI>
__global__ __launch_bounds__(512, 1) void gemm256(
    const __hip_bfloat16* __restrict__ A, const __hip_bfloat16* __restrict__ Bt,
    void* __restrict__ Cout, const float* __restrict__ bias, float scale,
    int K, int lda, int ldb, int ldc,
    long strideA, long strideB, long strideC)
{
    __shared__ __align__(16) char smem[131072];

    const int b = blockIdx.z;
    const int tid = threadIdx.x;
    const int lane = tid & 63;
    const int wm = (tid >> 6) & 1;
    const int wn = (tid >> 6) >> 1;

    const __hip_bfloat16* gA = A + (long)b * strideA + (long)blockIdx.x * 256 * lda;
    const __hip_bfloat16* gB = Bt + (long)b * strideB + (long)blockIdx.y * 256 * ldb;

    const int r0 = tid >> 3;
    const int s0 = (tid & 7) ^ (r0 & 7);
    const int r1 = r0 + 64;
    const int s1 = (tid & 7) ^ (r1 & 7);

#define STAGE(buf, isB, half, kt)                                                        \
    do {                                                                                 \
        const __hip_bfloat16* g_ = (isB) ? gB : gA;                                      \
        const int ld_ = (isB) ? ldb : lda;                                               \
        char* l_ = smem + (buf) * 65536 + (isB) * 32768 + (half) * 16384;                \
        gload_lds16(g_ + (long)((half) * 128 + r0) * ld_ + (kt) * 64 + s0 * 8, l_ + tid * 16);        \
        gload_lds16(g_ + (long)((half) * 128 + r1) * ld_ + (kt) * 64 + s1 * 8, l_ + 8192 + tid * 16); \
    } while (0)

    const int fr = lane & 15;
    const int kg = lane >> 4;

#define LDA_(dst, buf, mh, mi, kk)                                                       \
    do {                                                                                 \
        const int lr_ = wm * 64 + (mi) * 16 + fr;                                        \
        const int sl_ = ((kk) * 4 + kg) ^ (lr_ & 7);                                     \
        dst = *(const bf16x8*)(smem + (buf) * 65536 + (mh) * 16384 + lr_ * 128 + sl_ * 16); \
    } while (0)
#define LDB_(dst, buf, nh, ni, kk)                                                       \
    do {                                                                                 \
        const int lr_ = wn * 32 + (ni) * 16 + fr;                                        \
        const int sl_ = ((kk) * 4 + kg) ^ (lr_ & 7);                                     \
        dst = *(const bf16x8*)(smem + (buf) * 65536 + 32768 + (nh) * 16384 + lr_ * 128 + sl_ * 16); \
    } while (0)

    f32x4 acc[2][2][4][2];
#pragma unroll
    for (int mh = 0; mh < 2; ++mh)
#pragma unroll
        for (int nh = 0; nh < 2; ++nh)
#pragma unroll
            for (int mi = 0; mi < 4; ++mi)
#pragma unroll
                for (int ni = 0; ni < 2; ++ni) acc[mh][nh][mi][ni] = {0.f, 0.f, 0.f, 0.f};

    bf16x8 av[4][2], bv[2][2];

#define MFMA_QUAD(mh, nh)                                                                \
    do {                                                                                 \
        __builtin_amdgcn_s_setprio(1);                                                   \
        _Pragma("unroll")                                                                \
        for (int mi = 0; mi < 4; ++mi)                                                   \
            _Pragma("unroll")                                                            \
            for (int ni = 0; ni < 2; ++ni)                                               \
                _Pragma("unroll")                                                        \
                for (int kk = 0; kk < 2; ++kk)                                           \
                    acc[mh][nh][mi][ni] = __builtin_amdgcn_mfma_f32_16x16x32_bf16(       \
                        av[mi][kk], bv[ni][kk], acc[mh][nh][mi][ni], 0, 0, 0);           \
        __builtin_amdgcn_s_setprio(0);                                                   \
    } while (0)

    const int NT = K >> 6;

    STAGE(0, 0, 0, 0);
    STAGE(0, 1, 0, 0);
    STAGE(0, 1, 1, 0);
    STAGE(0, 0, 1, 0);
    WAITV(4);
    SYNC();

    for (int t = 0; t < NT - 1; ++t) {
        const int c = t & 1;
#pragma unroll
        for (int mi = 0; mi < 4; ++mi) { LDA_(av[mi][0], c, 0, mi, 0); LDA_(av[mi][1], c, 0, mi, 1); }
#pragma unroll
        for (int ni = 0; ni < 2; ++ni) { LDB_(bv[ni][0], c, 0, ni, 0); LDB_(bv[ni][1], c, 0, ni, 1); }
        STAGE(c ^ 1, 0, 0, t + 1);
        MFMA_QUAD(0, 0);
        WAITV(4);
        SYNC();
#pragma unroll
        for (int ni = 0; ni < 2; ++ni) { LDB_(bv[ni][0], c, 1, ni, 0); LDB_(bv[ni][1], c, 1, ni, 1); }
        STAGE(c ^ 1, 1, 0, t + 1);
        MFMA_QUAD(0, 1);
        WAITV(4);
        SYNC();
#pragma unroll
        for (int mi = 0; mi < 4; ++mi) { LDA_(av[mi][0], c, 1, mi, 0); LDA_(av[mi][1], c, 1, mi, 1); }
        STAGE(c ^ 1, 1, 1, t + 1);
        MFMA_QUAD(1, 1);
        SYNC();
#pragma unroll
        for (int ni = 0; ni < 2; ++ni) { LDB_(bv[ni][0], c, 0, ni, 0); LDB_(bv[ni][1], c, 0, ni, 1); }
        STAGE(c ^ 1, 0, 1, t + 1);
        MFMA_QUAD(1, 0);
        WAITV(4);
        SYNC();
    }

    {
        const int c = (NT - 1) & 1;
#pragma unroll
        for (int mi = 0; mi < 4; ++mi) { LDA_(av[mi][0], c, 0, mi, 0); LDA_(av[mi][1], c, 0, mi, 1); }
#pragma unroll
        for (int ni = 0; ni < 2; ++ni) { LDB_(bv[ni][0], c, 0, ni, 0); LDB_(bv[ni][1], c, 0, ni, 1); }
        MFMA_QUAD(0, 0);
        WAITV(2);
        SYNC();
#pragma unroll
        for (int ni = 0; ni < 2; ++ni) { LDB_(bv[ni][0], c, 1, ni, 0); LDB_(bv[ni][1], c, 1, ni, 1); }
        MFMA_QUAD(0, 1);
        WAITV(0);
        SYNC();
#pragma unroll
        for (int mi = 0; mi < 4; ++mi) { LDA_(av[mi][0], c, 1, mi, 0); LDA_(av[mi][1], c, 1, mi, 1); }
        MFMA_QUAD(1, 1);
#pragma unroll
        for (int ni = 0; ni < 2; ++ni) { LDB_(bv[ni][0], c, 0, ni, 0); LDB_(bv[ni][1], c, 0, ni, 1); }
        MFMA_QUAD(1, 0);
    }

    const long row0 = (long)blockIdx.x * 256 + wm * 64 + (lane >> 4) * 4;
    const long col0 = (long)blockIdx.y * 256 + wn * 32 + (lane & 15);
#pragma unroll
    for (int mh = 0; mh < 2; ++mh) {
#pragma unroll
        for (int nh = 0; nh < 2; ++nh) {
#pragma unroll
            for (int ni = 0; ni < 2; ++ni) {
                const long col = col0 + nh * 128 + ni * 16;
                const float bval = (EPI != 1 && bias != nullptr) ? bias[col] : 0.f;
#pragma unroll
                for (int mi = 0; mi < 4; ++mi) {
#pragma unroll
                    for (int i = 0; i < 4; ++i) {
                        const long row = row0 + mh * 128 + mi * 16 + i;
                        const float v = acc[mh][nh][mi][ni][i];
                        const long idx = (long)b * strideC + row * (long)ldc + col;
                        if (EPI == 1) ((__hip_bfloat16*)Cout)[idx] = __float2bfloat16(v * scale);
                        else if (EPI == 0) ((__hip_bfloat16*)Cout)[idx] = __float2bfloat16(v + bval);
                        else ((float*)Cout)[idx] = v + bval;
                    }
                }
            }
        }
    }
#undef STAGE
#undef LDA_
#undef LDB_
#undef MFMA_QUAD
}

// ---------------------------------------------------------------------------
// out[c][r] = (bf16) in[r][c] ; LDS-tiled 32x32, block (32,8)
// ---------------------------------------------------------------------------
template <typename TIN>
__global__ __launch_bounds__(256) void transpose_to_bf16(
    const TIN* __restrict__ in, __hip_bfloat16* __restrict__ out,
    int R, int C, int ldIn, long sIn, long sOut)
{
    __shared__ float tile[32][33];
    const int b = blockIdx.z;
    const TIN* pin = in + (long)b * sIn;
    __hip_bfloat16* pout = out + (long)b * sOut;
    const int tx = threadIdx.x, ty = threadIdx.y;
    const int c0 = blockIdx.x * 32, r0 = blockIdx.y * 32;
#pragma unroll
    for (int j = 0; j < 4; ++j)
        tile[ty + j * 8][tx] = to_f32(pin[(long)(r0 + ty + j * 8) * ldIn + c0 + tx]);
    __syncthreads();
#pragma unroll
    for (int j = 0; j < 4; ++j)
        pout[(long)(c0 + ty + j * 8) * R + r0 + tx] = __float2bfloat16(tile[tx][ty + j * 8]);
}

// ---------------------------------------------------------------------------
__global__ __launch_bounds__(256) void f32_to_bf16_vec(
    const float* __restrict__ in, __hip_bfloat16* __restrict__ out, long n4)
{
    const long i = (long)blockIdx.x * 256 + threadIdx.x;
    if (i >= n4) return;
    const float4 v = ((const float4*)in)[i];
    union { __hip_bfloat16 h[4]; ushort4 u; } cv;
    cv.h[0] = __float2bfloat16(v.x);
    cv.h[1] = __float2bfloat16(v.y);
    cv.h[2] = __float2bfloat16(v.z);
    cv.h[3] = __float2bfloat16(v.w);
    ((ushort4*)out)[i] = cv.u;
}

// ---------------------------------------------------------------------------
// bias concat: [bq bk bv | bo bgv bgg]  (6144 floats)
// ---------------------------------------------------------------------------
__global__ __launch_bounds__(256) void concat_bias(
    const float* __restrict__ bq, const float* __restrict__ bk, const float* __restrict__ bv,
    const float* __restrict__ bo, const float* __restrict__ bgv, const float* __restrict__ bgg,
    float* __restrict__ out)
{
    const int i = blockIdx.x * 256 + threadIdx.x;  // 6144 total
    float v;
    if (i < 1024) v = bq[i];
    else if (i < 2048) v = bk[i - 1024];
    else if (i < 3072) v = bv[i - 2048];
    else if (i < 4096) v = bo[i - 3072];
    else if (i < 5120) v = bgv[i - 4096];
    else v = bgg[i - 5120];
    out[i] = v;
}

// ---------------------------------------------------------------------------
// row softmax: bf16 scores row (2048) -> bf16 probs; lane handles 8 contiguous
// ---------------------------------------------------------------------------
__global__ __launch_bounds__(256) void softmax_kernel(
    const __hip_bfloat16* __restrict__ S, __hip_bfloat16* __restrict__ P)
{
    const long row = blockIdx.x;
    const __hip_bfloat16* s = S + row * 2048;
    __hip_bfloat16* p = P + row * 2048;
    const int t = threadIdx.x;
    const bf16x8 v8 = *(const bf16x8*)(s + t * 8);
    float v[8];
    float mx = -1e30f;
#pragma unroll
    for (int j = 0; j < 8; ++j) { v[j] = (float)v8[j]; mx = fmaxf(mx, v[j]); }
#pragma unroll
    for (int off = 32; off; off >>= 1) mx = fmaxf(mx, __shfl_xor(mx, off));
    __shared__ float wred[4];
    __shared__ float wsum[4];
    const int w = t >> 6;
    if ((t & 63) == 0) wred[w] = mx;
    __syncthreads();
    mx = fmaxf(fmaxf(wred[0], wred[1]), fmaxf(wred[2], wred[3]));
    float sum = 0.f;
#pragma unroll
    for (int j = 0; j < 8; ++j) { v[j] = __expf(v[j] - mx); sum += v[j]; }
#pragma unroll
    for (int off = 32; off; off >>= 1) sum += __shfl_xor(sum, off);
    if ((t & 63) == 0) wsum[w] = sum;
    __syncthreads();
    sum = wsum[0] + wsum[1] + wsum[2] + wsum[3];
    const float inv = 1.0f / sum;
    bf16x8 o8;
#pragma unroll
    for (int j = 0; j < 8; ++j) o8[j] = (__bf16)(v[j] * inv);
    *(bf16x8*)(p + t * 8) = o8;
}

// ---------------------------------------------------------------------------
// T1G: bf16 [row][3072] = [T1 | Gval | Ggate]. y = T1 + Gv*sigmoid(Gg);
// out = LN(y)*gamma + beta (f32). One block per row; lane handles 4 contiguous.
// ---------------------------------------------------------------------------
__global__ __launch_bounds__(256) void glu_ln_kernel(
    const __hip_bfloat16* __restrict__ T1G,
    const float* __restrict__ gamma, const float* __restrict__ beta, float* __restrict__ out)
{
    const long row = blockIdx.x;
    const __hip_bfloat16* pr = T1G + row * 3072;
    const int t = threadIdx.x;
    const int c0 = t * 4;
    const bf16x4 t1 = *(const bf16x4*)(pr + c0);
    const bf16x4 gv = *(const bf16x4*)(pr + 1024 + c0);
    const bf16x4 gg = *(const bf16x4*)(pr + 2048 + c0);
    float y[4];
    float s = 0.f, ss = 0.f;
#pragma unroll
    for (int j = 0; j < 4; ++j) {
        const float g = (float)gv[j] * (1.0f / (1.0f + __expf(-(float)gg[j])));
        const float val = (float)t1[j] + g;
        y[j] = val; s += val; ss += val * val;
    }
#pragma unroll
    for (int off = 32; off; off >>= 1) { s += __shfl_xor(s, off); ss += __shfl_xor(ss, off); }
    __shared__ float rs[4], rss[4];
    const int w = t >> 6;
    if ((t & 63) == 0) { rs[w] = s; rss[w] = ss; }
    __syncthreads();
    s = rs[0] + rs[1] + rs[2] + rs[3];
    ss = rss[0] + rss[1] + rss[2] + rss[3];
    const float mu = s * (1.0f / 1024.0f);
    const float var = ss * (1.0f / 1024.0f) - mu * mu;
    const float r = rsqrtf(var + 1e-5f);
    const float4 gm = *(const float4*)(gamma + c0);
    const float4 bt = *(const float4*)(beta + c0);
    float4 o;
    o.x = (y[0] - mu) * r * gm.x + bt.x;
    o.y = (y[1] - mu) * r * gm.y + bt.y;
    o.z = (y[2] - mu) * r * gm.z + bt.z;
    o.w = (y[3] - mu) * r * gm.w + bt.w;
    *(float4*)(out + row * 1024 + c0) = o;
}

// ---------------------------------------------------------------------------
extern "C" void kernel_launch(void* const* d_in, const int* in_sizes, int n_in,
                              void* d_out, int out_size, void* d_ws, size_t ws_size,
                              hipStream_t stream)
{
    const int B = 4, S = 2048, D = 1024;
    const float* x    = (const float*)d_in[0];
    const float* Wq   = (const float*)d_in[1];
    const float* bq   = (const float*)d_in[2];
    const float* Wk   = (const float*)d_in[3];
    const float* bk   = (const float*)d_in[4];
    const float* Wv   = (const float*)d_in[5];
    const float* bv   = (const float*)d_in[6];
    const float* Wo   = (const float*)d_in[7];
    const float* bo   = (const float*)d_in[8];
    const float* Wgv  = (const float*)d_in[9];
    const float* bgv  = (const float*)d_in[10];
    const float* Wgg  = (const float*)d_in[11];
    const float* bgg  = (const float*)d_in[12];
    const float* gamma = (const float*)d_in[13];
    const float* beta  = (const float*)d_in[14];
    float* out = (float*)d_out;

    char* ws = (char*)d_ws;
    size_t off = 0;
    auto take = [&](size_t bytes) { char* p = ws + off; off += (bytes + 255) & ~(size_t)255; return p; };

    __hip_bfloat16* wqkv_t = (__hip_bfloat16*)take((size_t)3 * D * D * 2);  // [3D][D] rows: Wq^T,Wk^T,Wv^T
    __hip_bfloat16* wog_t  = (__hip_bfloat16*)take((size_t)3 * D * D * 2);  // [3D][D] rows: Wo^T,Wgv^T,Wgg^T
    float*          bcat   = (float*)take((size_t)6 * D * 4);               // [bqkv | bo,bgv,bgg]
    __hip_bfloat16* xb     = (__hip_bfloat16*)take((size_t)B * S * D * 2);
    __hip_bfloat16* QKVb   = (__hip_bfloat16*)take((size_t)B * S * 3 * D * 2); // [B*S][3D]
    __hip_bfloat16* Vtb    = (__hip_bfloat16*)take((size_t)B * S * D * 2);     // [B][D][S]
    __hip_bfloat16* scoresb = (__hip_bfloat16*)take((size_t)B * S * S * 2);    // 32 MiB bf16
    __hip_bfloat16* Pb     = (__hip_bfloat16*)take((size_t)B * S * S * 2);     // 32 MiB
    __hip_bfloat16* Oatt   = (__hip_bfloat16*)take((size_t)B * S * D * 2);
    __hip_bfloat16* T1G    = (__hip_bfloat16*)take((size_t)B * S * 3 * D * 2); // [B*S][3072] bf16

    const long SD = (long)S * D, SS = (long)S * S, S3D = (long)S * 3 * D;
    const float att_scale = 0.03125f;  // 1/sqrt(1024)
    const __hip_bfloat16* Qb = QKVb;
    const __hip_bfloat16* Kb = QKVb + D;
    const __hip_bfloat16* Vb = QKVb + 2 * D;

    // 1. casts / weight transposes (Wt[e][d] = W[d][e] -> every GEMM is bt-format)
    f32_to_bf16_vec<<<dim3((unsigned)((long)B * S * D / 4 / 256)), dim3(256), 0, stream>>>(x, xb, (long)B * S * D / 4);
    transpose_to_bf16<float><<<dim3(D / 32, D / 32, 1), dim3(32, 8), 0, stream>>>(Wq,  wqkv_t,             D, D, D, 0, 0);
    transpose_to_bf16<float><<<dim3(D / 32, D / 32, 1), dim3(32, 8), 0, stream>>>(Wk,  wqkv_t + D * D,     D, D, D, 0, 0);
    transpose_to_bf16<float><<<dim3(D / 32, D / 32, 1), dim3(32, 8), 0, stream>>>(Wv,  wqkv_t + 2 * D * D, D, D, D, 0, 0);
    transpose_to_bf16<float><<<dim3(D / 32, D / 32, 1), dim3(32, 8), 0, stream>>>(Wo,  wog_t,              D, D, D, 0, 0);
    transpose_to_bf16<float><<<dim3(D / 32, D / 32, 1), dim3(32, 8), 0, stream>>>(Wgv, wog_t + D * D,      D, D, D, 0, 0);
    transpose_to_bf16<float><<<dim3(D / 32, D / 32, 1), dim3(32, 8), 0, stream>>>(Wgg, wog_t + 2 * D * D,  D, D, D, 0, 0);
    concat_bias<<<dim3(24), dim3(256), 0, stream>>>(bq, bk, bv, bo, bgv, bgg, bcat);

    // 2. fused QKV projection: [8192][1024] x [3072][1024]^T -> [8192][3072] bf16  (768 blocks)
    gemm_tn128<<<dim3(B * S / 256, 3 * D / 128, 1), dim3(512), 0, stream>>>(
        xb, D, xb, D, 1 << 30, wqkv_t, QKVb, bcat, D, D, 3 * D, 0, 0, 0);

    // 3. scores = scale * Q K^T (bf16 out), per batch  (256 blocks)
    gemm256<1><<<dim3(S / 256, S / 256, B), dim3(512), 0, stream>>>(
        Qb, Kb, scoresb, nullptr, att_scale, D, 3 * D, 3 * D, S, S3D, S3D, SS);

    // 4. row softmax -> bf16 P
    softmax_kernel<<<dim3(B * S), dim3(256), 0, stream>>>(scoresb, Pb);

    // 5. V^T per batch, then Oatt = P @ V  (256 blocks)
    transpose_to_bf16<__hip_bfloat16><<<dim3(D / 32, S / 32, B), dim3(32, 8), 0, stream>>>(
        Vb, Vtb, S, D, 3 * D, S3D, SD);
    gemm_tn128<<<dim3(S / 256, D / 128, B), dim3(512), 0, stream>>>(
        Pb, S, Pb, S, 1 << 30, Vtb, Oatt, nullptr, S, S, D, SS, SD, SD);

    // 6. fused [T1 | GLUval | GLUgate]: cols<1024 use Oatt@Wo, cols>=1024 use Q@Wg  (768 blocks)
    gemm_tn128<<<dim3(B * S / 256, 3 * D / 128, 1), dim3(512), 0, stream>>>(
        Oatt, D, QKVb, 3 * D, D, wog_t, T1G, bcat + 3 * D, D, D, 3 * D, 0, 0, 0);

    // 7. y = T1 + Gval*sigmoid(Ggate); out = LayerNorm(y)*gamma+beta
    glu_ln_kernel<<<dim3(B * S), dim3(256), 0, stream>>>(T1G, gamma, beta, out);
}